// Round 10
// baseline (274.970 us; speedup 1.0000x reference)
//
#include <hip/hip_runtime.h>

// Fastformer additive attention, MI355X (round 9): occupancy-fixed stages.
// Round 8's unroll+prefetch in stage_soft raised VGPR to 192 -> 2 waves/SIMD
// -> 63 us/stage (REGRESSION). This round: 32 rows/block, no unroll, no
// manual prefetch, __launch_bounds__(256,4) to cap at 128 VGPR; hide latency
// with TLP (2048 blocks) instead of ILP.
//   conv:  w_qkv|w_out|wq|wk|x  f32 -> bf16 (ws)
//   QKV:   qkv[8192][1536] = x @ w_qkv^T + b_qkv (+ fused qs/ks rowsums)
//   stage1: qg = softmax((q.wq+bq)*S) . qs
//   stage2: kg = softmax((qg*(k.wk)+bk)*S) . (qg*ks)  (+ fused U = V*kg)
//   OUT:   out = U @ w_out^T + b_out + qo
// Logits bounded (|l|<~2) -> softmax without max subtraction, z/w linear.

#define SCL 0.125f
typedef unsigned short u16;
typedef __attribute__((ext_vector_type(8))) short short8;   // 8 bf16 = 4 VGPR
typedef __attribute__((ext_vector_type(4))) float f32x4;

#define MFMA16(a, b, c) __builtin_amdgcn_mfma_f32_16x16x32_bf16((a), (b), (c), 0, 0, 0)

__device__ __forceinline__ float bf2f(u16 u) {
    union { unsigned int i; float f; } v; v.i = ((unsigned int)u) << 16; return v.f;
}
__device__ __forceinline__ u16 f2bf(float f) {
    union { float f; unsigned int i; } v; v.f = f;
    unsigned int x = v.i;
    return (u16)((x + 0x7FFFu + ((x >> 16) & 1u)) >> 16);
}
__device__ __forceinline__ uint4 pack8(const float* v) {
    union { u16 u[8]; uint4 q; } r;
#pragma unroll
    for (int i = 0; i < 8; ++i) r.u[i] = f2bf(v[i]);
    return r.q;
}

// ---------------------------------------------------------------------------
// f32 -> bf16: w_qkv | w_out | wq | wk | x   (contiguous ws block)
// ---------------------------------------------------------------------------
__global__ __launch_bounds__(256) void conv_kernel(
    const float* __restrict__ w_qkv, const float* __restrict__ w_out,
    const float* __restrict__ wq, const float* __restrict__ wk,
    const float* __restrict__ x, u16* __restrict__ wsb)
{
    const int idx = (blockIdx.x * 256 + threadIdx.x) * 4;
    const float* src; int off;
    if      (idx < 786432)  { src = w_qkv; off = idx; }
    else if (idx < 1048576) { src = w_out; off = idx - 786432; }
    else if (idx < 1114112) { src = wq;    off = idx - 1048576; }
    else if (idx < 1179648) { src = wk;    off = idx - 1114112; }
    else                    { src = x;     off = idx - 1179648; }
    float4 v = *(const float4*)(src + off);
    ushort4 o; o.x = f2bf(v.x); o.y = f2bf(v.y); o.z = f2bf(v.z); o.w = f2bf(v.w);
    *(ushort4*)(wsb + idx) = o;
}

// ---------------------------------------------------------------------------
// 128x128 MFMA GEMM, BK=32, K=512, 256 thr (4 waves, 2x2 quadrants of 64x64).
// Register-prefetch of k-tile t+1 overlaps the ds_read+MFMA phase (neutral
// in round 8; kept).
//  MQKV: C=bf16 qkv ws (+b_qkv), fused per-head rowsums -> qs/ks
//  MOUT: C=f32 out (+b_out + qo residual)
// ---------------------------------------------------------------------------
#define MQKV 0
#define MOUT 1

template <int MODE>
__global__ __launch_bounds__(256) void gemm128(
    const u16* __restrict__ Ab, int lda, int acol,
    const u16* __restrict__ Wb, int ldb,
    const float* __restrict__ biasf,
    const u16* __restrict__ qkro,
    float* __restrict__ qsv, float* __restrict__ ksv,
    u16* __restrict__ Cws, float* __restrict__ outp)
{
    __shared__ u16 S[8192];          // 16 KB
    u16* As = S;                     // [128][32]
    u16* Bs = S + 4096;              // [128][32]

    const int t = threadIdx.x;
    const int w = t >> 6, lane = t & 63, s = lane & 15, quad = lane >> 4;
    const int wr = w >> 1, wc = w & 1;
    const int bm = blockIdx.x * 128, jn0 = blockIdx.y * 128;
    const int arow = t >> 1, ac0 = (t & 1) * 16;

    const u16* aptr = Ab + (size_t)(bm + arow) * lda + acol + ac0;
    const u16* bptr = Wb + (size_t)(jn0 + arow) * ldb + ac0;

    f32x4 acc[4][4];
#pragma unroll
    for (int i = 0; i < 4; ++i)
#pragma unroll
        for (int j = 0; j < 4; ++j) acc[i][j] = (f32x4){0.f, 0.f, 0.f, 0.f};

    uint4 ga0 = *(const uint4*)aptr,        ga1 = *(const uint4*)(aptr + 8);
    uint4 gb0 = *(const uint4*)bptr,        gb1 = *(const uint4*)(bptr + 8);

    for (int kt = 0; kt < 512; kt += 32) {
        __syncthreads();
        *(uint4*)&As[arow * 32 + ac0]     = ga0;
        *(uint4*)&As[arow * 32 + ac0 + 8] = ga1;
        *(uint4*)&Bs[arow * 32 + ac0]     = gb0;
        *(uint4*)&Bs[arow * 32 + ac0 + 8] = gb1;
        __syncthreads();
        if (kt + 32 < 512) {            // prefetch next tile (in flight w/ MFMA)
            ga0 = *(const uint4*)(aptr + kt + 32);
            ga1 = *(const uint4*)(aptr + kt + 40);
            gb0 = *(const uint4*)(bptr + kt + 32);
            gb1 = *(const uint4*)(bptr + kt + 40);
        }
        short8 af[4], bf[4];
#pragma unroll
        for (int mt = 0; mt < 4; ++mt)
            af[mt] = *(const short8*)&As[(wr * 64 + mt * 16 + s) * 32 + quad * 8];
#pragma unroll
        for (int ct = 0; ct < 4; ++ct)
            bf[ct] = *(const short8*)&Bs[(wc * 64 + ct * 16 + s) * 32 + quad * 8];
#pragma unroll
        for (int mt = 0; mt < 4; ++mt)
#pragma unroll
            for (int ct = 0; ct < 4; ++ct)
                acc[mt][ct] = MFMA16(af[mt], bf[ct], acc[mt][ct]);
    }

    float bb[4];
#pragma unroll
    for (int ct = 0; ct < 4; ++ct) bb[ct] = biasf[jn0 + wc * 64 + ct * 16 + s];

    if constexpr (MODE == MOUT) {
#pragma unroll
        for (int mt = 0; mt < 4; ++mt)
#pragma unroll
            for (int ct = 0; ct < 4; ++ct) {
                const int col = jn0 + wc * 64 + ct * 16 + s;
#pragma unroll
                for (int r = 0; r < 4; ++r) {
                    const int row = bm + wr * 64 + mt * 16 + quad * 4 + r;
                    outp[(size_t)row * 512 + col] =
                        acc[mt][ct][r] + bb[ct] + bf2f(qkro[(size_t)row * 1536 + col]);
                }
            }
    } else {
        // fused per-head row sums (each 64-col wave quadrant = one head)
        const int c0 = jn0 + wc * 64;
        if (c0 < 1024) {
            const int h = (c0 & 511) >> 6;
            float* dst = (c0 < 512) ? qsv : ksv;
#pragma unroll
            for (int mt = 0; mt < 4; ++mt)
#pragma unroll
                for (int r = 0; r < 4; ++r) {
                    float v = (acc[mt][0][r] + bb[0]) + (acc[mt][1][r] + bb[1]) +
                              (acc[mt][2][r] + bb[2]) + (acc[mt][3][r] + bb[3]);
                    v += __shfl_xor(v, 1); v += __shfl_xor(v, 2);
                    v += __shfl_xor(v, 4); v += __shfl_xor(v, 8);
                    if (s == 0) {
                        const int row = bm + wr * 64 + mt * 16 + quad * 4 + r;
                        dst[((((row >> 10) << 3) + h) << 10) | (row & 1023)] = v;
                    }
                }
        }
        // bf16 pack + coalesced store via LDS bounce (two 64-row halves)
#pragma unroll
        for (int half = 0; half < 2; ++half) {
            __syncthreads();
            if (wr == half) {
#pragma unroll
                for (int mt = 0; mt < 4; ++mt)
#pragma unroll
                    for (int ct = 0; ct < 4; ++ct)
#pragma unroll
                        for (int r = 0; r < 4; ++r)
                            S[(mt * 16 + quad * 4 + r) * 128 + wc * 64 + ct * 16 + s] =
                                f2bf(acc[mt][ct][r] + bb[ct]);
            }
            __syncthreads();
            const int row = t >> 2, coff = (t & 3) * 32;
            u16* dp = Cws + (size_t)(bm + half * 64 + row) * 1536 + jn0 + coff;
#pragma unroll
            for (int i = 0; i < 4; ++i)
                *(uint4*)(dp + i * 8) = *(const uint4*)&S[row * 128 + coff + i * 8];
        }
    }
}

// ---------------------------------------------------------------------------
// Softmax stage. Block: 32 n-rows x one (b,h); wave w covers m in
// [w*256, (w+1)*256). Low register footprint (qa[2][2], launch_bounds 4
// waves/EU -> <=128 VGPR); latency hidden by TLP (2048 blocks).
//   stage1<false>: qcol0=0,   rowscale=null, wv=qs
//   stage2<true>:  qcol0=512, rowscale=qg,   wv=qg*ks  (+ U=V*kg tail)
// ---------------------------------------------------------------------------
template <bool DOU>
__global__ __launch_bounds__(256, 4) void stage_soft(
    u16* __restrict__ qkws, int qcol0,
    const u16* __restrict__ wmb, const float* __restrict__ biasv,
    const float* __restrict__ rowscale,
    const float* __restrict__ wv1, const float* __restrict__ wv2,
    float* __restrict__ outg)
{
    __shared__ float zr[4][32], wrs[4][32], kgv[32];
    const int t = threadIdx.x;
    const int w = t >> 6, lane = t & 63, s = lane & 15, quad = lane >> 4;
    const int n0 = blockIdx.x * 32;
    const int bh = blockIdx.y, b = bh >> 3, h = bh & 7;

    short8 qa[2][2];
#pragma unroll
    for (int nt = 0; nt < 2; ++nt)
#pragma unroll
        for (int kk = 0; kk < 2; ++kk)
            qa[nt][kk] = *(const short8*)&qkws[
                (size_t)((b << 10) + n0 + nt * 16 + s) * 1536 + qcol0 + (h << 6) + kk * 32 + quad * 8];

    float rs[2][4];
#pragma unroll
    for (int nt = 0; nt < 2; ++nt)
#pragma unroll
        for (int r = 0; r < 4; ++r)
            rs[nt][r] = rowscale ? rowscale[(bh << 10) + n0 + nt * 16 + quad * 4 + r] : 1.0f;

    float z[2][4] = {}, wa[2][4] = {};

    for (int mi = 0; mi < 16; ++mi) {
        const int mt = w * 256 + mi * 16;
        const u16* bp = wmb + (size_t)(mt + s) * 64 + quad * 8;
        short8 bf0 = *(const short8*)bp;
        short8 bf1 = *(const short8*)(bp + 32);
        const float bm = biasv[mt + s];
        float wv = wv1[(bh << 10) + mt + s];
        if (wv2) wv *= wv2[(bh << 10) + mt + s];
#pragma unroll
        for (int nt = 0; nt < 2; ++nt) {
            f32x4 a = (f32x4){0.f, 0.f, 0.f, 0.f};
            a = MFMA16(qa[nt][0], bf0, a);
            a = MFMA16(qa[nt][1], bf1, a);
#pragma unroll
            for (int r = 0; r < 4; ++r) {
                const float l = (rs[nt][r] * a[r] + bm) * SCL;
                const float e = __expf(l);
                z[nt][r] += e;
                wa[nt][r] += e * wv;
            }
        }
    }

#pragma unroll
    for (int nt = 0; nt < 2; ++nt)
#pragma unroll
        for (int r = 0; r < 4; ++r) {
            float Z = z[nt][r], W = wa[nt][r];
            for (int off = 1; off < 16; off <<= 1) {
                Z += __shfl_xor(Z, off);
                W += __shfl_xor(W, off);
            }
            if (s == 0) {
                zr[w][nt * 16 + quad * 4 + r] = Z;
                wrs[w][nt * 16 + quad * 4 + r] = W;
            }
        }
    __syncthreads();
    if (t < 32) {
        const float Z = zr[0][t] + zr[1][t] + zr[2][t] + zr[3][t];
        const float W = wrs[0][t] + wrs[1][t] + wrs[2][t] + wrs[3][t];
        const float v = W / Z;
        outg[(bh << 10) + n0 + t] = v;
        kgv[t] = v;
    }
    if constexpr (DOU) {
        __syncthreads();
        const int rl = t >> 3, d0 = (t & 7) * 8;   // 32 rows x 64 cols
        const float kgf = kgv[rl];
        const size_t base = (size_t)((b << 10) + n0 + rl) * 1536 + (h << 6) + d0;
        union { uint4 q; u16 u[8]; } vv;
        vv.q = *(const uint4*)&qkws[base + 1024];
        float tmp[8];
#pragma unroll
        for (int j = 0; j < 8; ++j) tmp[j] = bf2f(vv.u[j]) * kgf;
        *(uint4*)&qkws[base + 512] = pack8(tmp);
    }
}

// ---------------------------------------------------------------------------
extern "C" void kernel_launch(void* const* d_in, const int* in_sizes, int n_in,
                              void* d_out, int out_size, void* d_ws, size_t ws_size,
                              hipStream_t stream)
{
    const float* x     = (const float*)d_in[0];
    const float* w_qkv = (const float*)d_in[1];
    const float* b_qkv = (const float*)d_in[2];
    const float* wq    = (const float*)d_in[3];
    const float* bq    = (const float*)d_in[4];
    const float* wk    = (const float*)d_in[5];
    const float* bk    = (const float*)d_in[6];
    const float* w_out = (const float*)d_in[7];
    const float* b_out = (const float*)d_in[8];
    float* out = (float*)d_out;

    // ws: qs|ks|qg|kg (65536 f32) | bf16: wqkv|wout|wq|wk|x | qkv ws bf16
    float* qs = (float*)d_ws;
    float* ks = qs + 65536;
    float* qg = ks + 65536;
    float* kg = qg + 65536;
    u16* wsb   = (u16*)(kg + 65536);
    u16* wqkvb = wsb;
    u16* woutb = wqkvb + 786432;
    u16* wqb   = woutb + 262144;
    u16* wkb   = wqb + 65536;
    u16* xb    = wkb + 65536;
    u16* qkws  = xb + 4194304;

    conv_kernel<<<5248, 256, 0, stream>>>(w_qkv, w_out, wq, wk, x, wsb);
    // QKV GEMM + fused qs/ks rowsums
    gemm128<MQKV><<<dim3(64, 12), 256, 0, stream>>>(
        xb, 512, 0, wqkvb, 512, b_qkv, nullptr, qs, ks, qkws, nullptr);
    // stage 1 -> qg
    stage_soft<false><<<dim3(32, 64), 256, 0, stream>>>(
        qkws, 0, wqb, bq, nullptr, qs, nullptr, qg);
    // stage 2 -> kg, + fused U = V*kg into k-half
    stage_soft<true><<<dim3(32, 64), 256, 0, stream>>>(
        qkws, 512, wkb, bk, qg, qg, ks, kg);
    // OUT: out = U @ w_out^T + b_out + qo
    gemm128<MOUT><<<dim3(64, 4), 256, 0, stream>>>(
        qkws, 1536, 512, woutb, 512, b_out, qkws, nullptr, nullptr, nullptr, out);
}

// Round 11
// 191.874 us; speedup vs baseline: 1.4331x; 1.4331x over previous
//
#include <hip/hip_runtime.h>

// Fastformer additive attention, MI355X (round 10): revert to round-7 (best
// measured, 190 us) + single change: __launch_bounds__(256,4) on stage_soft
// to pin it at <=128 VGPR / 4 waves per SIMD. Rounds 8-10's ILP/TLP variants
// all regressed; per-block structure here is the measured optimum.
//   conv:  w_qkv|w_out|wq|wk|x  f32 -> bf16 (ws)
//   QKV:   qkv[8192][1536] = x @ w_qkv^T + b_qkv (+ fused qs/ks rowsums)
//   stage1: qg = softmax((q.wq+bq)*S) . qs
//   stage2: kg = softmax((qg*(k.wk)+bk)*S) . (qg*ks)  (+ fused U = V*kg)
//   OUT:   out = U @ w_out^T + b_out + qo
// Logits bounded (|l|<~2) -> softmax without max subtraction, z/w linear.

#define SCL 0.125f
typedef unsigned short u16;
typedef __attribute__((ext_vector_type(8))) short short8;   // 8 bf16 = 4 VGPR
typedef __attribute__((ext_vector_type(4))) float f32x4;

#define MFMA16(a, b, c) __builtin_amdgcn_mfma_f32_16x16x32_bf16((a), (b), (c), 0, 0, 0)

__device__ __forceinline__ float bf2f(u16 u) {
    union { unsigned int i; float f; } v; v.i = ((unsigned int)u) << 16; return v.f;
}
__device__ __forceinline__ u16 f2bf(float f) {
    union { float f; unsigned int i; } v; v.f = f;
    unsigned int x = v.i;
    return (u16)((x + 0x7FFFu + ((x >> 16) & 1u)) >> 16);
}
__device__ __forceinline__ uint4 pack8(const float* v) {
    union { u16 u[8]; uint4 q; } r;
#pragma unroll
    for (int i = 0; i < 8; ++i) r.u[i] = f2bf(v[i]);
    return r.q;
}

// ---------------------------------------------------------------------------
// f32 -> bf16: w_qkv | w_out | wq | wk | x   (contiguous ws block)
// ---------------------------------------------------------------------------
__global__ __launch_bounds__(256) void conv_kernel(
    const float* __restrict__ w_qkv, const float* __restrict__ w_out,
    const float* __restrict__ wq, const float* __restrict__ wk,
    const float* __restrict__ x, u16* __restrict__ wsb)
{
    const int idx = (blockIdx.x * 256 + threadIdx.x) * 4;
    const float* src; int off;
    if      (idx < 786432)  { src = w_qkv; off = idx; }
    else if (idx < 1048576) { src = w_out; off = idx - 786432; }
    else if (idx < 1114112) { src = wq;    off = idx - 1048576; }
    else if (idx < 1179648) { src = wk;    off = idx - 1114112; }
    else                    { src = x;     off = idx - 1179648; }
    float4 v = *(const float4*)(src + off);
    ushort4 o; o.x = f2bf(v.x); o.y = f2bf(v.y); o.z = f2bf(v.z); o.w = f2bf(v.w);
    *(ushort4*)(wsb + idx) = o;
}

// ---------------------------------------------------------------------------
// 128x128 MFMA GEMM, BK=32, K=512, 256 thr (4 waves in 2x2 quadrants, each
// 64x64 via 4x4 grid of 16x16x32). A/B bf16; acc f32.  [round-7 version]
//  MQKV: C=bf16 qkv ws (+b_qkv) with fused per-head rowsums -> qs/ks
//  MOUT: C=f32 out (+b_out + qo residual from q-half of qkv ws)
// ---------------------------------------------------------------------------
#define MQKV 0
#define MOUT 1

template <int MODE>
__global__ __launch_bounds__(256) void gemm128(
    const u16* __restrict__ Ab, int lda, int acol,
    const u16* __restrict__ Wb, int ldb,
    const float* __restrict__ biasf,
    const u16* __restrict__ qkro,
    float* __restrict__ qsv, float* __restrict__ ksv,
    u16* __restrict__ Cws, float* __restrict__ outp)
{
    __shared__ u16 S[8192];          // 16 KB
    u16* As = S;                     // [128][32]
    u16* Bs = S + 4096;              // [128][32]

    const int t = threadIdx.x;
    const int w = t >> 6, lane = t & 63, s = lane & 15, quad = lane >> 4;
    const int wr = w >> 1, wc = w & 1;
    const int bm = blockIdx.x * 128, jn0 = blockIdx.y * 128;
    const int arow = t >> 1, ac0 = (t & 1) * 16;

    f32x4 acc[4][4];
#pragma unroll
    for (int i = 0; i < 4; ++i)
#pragma unroll
        for (int j = 0; j < 4; ++j) acc[i][j] = (f32x4){0.f, 0.f, 0.f, 0.f};

    for (int kt = 0; kt < 512; kt += 32) {
        __syncthreads();
        {
            const u16* ap = Ab + (size_t)(bm + arow) * lda + acol + kt + ac0;
            *(uint4*)&As[arow * 32 + ac0]     = *(const uint4*)ap;
            *(uint4*)&As[arow * 32 + ac0 + 8] = *(const uint4*)(ap + 8);
            const u16* bp = Wb + (size_t)(jn0 + arow) * ldb + kt + ac0;
            *(uint4*)&Bs[arow * 32 + ac0]     = *(const uint4*)bp;
            *(uint4*)&Bs[arow * 32 + ac0 + 8] = *(const uint4*)(bp + 8);
        }
        __syncthreads();
        short8 af[4], bf[4];
#pragma unroll
        for (int mt = 0; mt < 4; ++mt)
            af[mt] = *(const short8*)&As[(wr * 64 + mt * 16 + s) * 32 + quad * 8];
#pragma unroll
        for (int ct = 0; ct < 4; ++ct)
            bf[ct] = *(const short8*)&Bs[(wc * 64 + ct * 16 + s) * 32 + quad * 8];
#pragma unroll
        for (int mt = 0; mt < 4; ++mt)
#pragma unroll
            for (int ct = 0; ct < 4; ++ct)
                acc[mt][ct] = MFMA16(af[mt], bf[ct], acc[mt][ct]);
    }

    float bb[4];
#pragma unroll
    for (int ct = 0; ct < 4; ++ct) bb[ct] = biasf[jn0 + wc * 64 + ct * 16 + s];

    if constexpr (MODE == MOUT) {
#pragma unroll
        for (int mt = 0; mt < 4; ++mt)
#pragma unroll
            for (int ct = 0; ct < 4; ++ct) {
                const int col = jn0 + wc * 64 + ct * 16 + s;
#pragma unroll
                for (int r = 0; r < 4; ++r) {
                    const int row = bm + wr * 64 + mt * 16 + quad * 4 + r;
                    outp[(size_t)row * 512 + col] =
                        acc[mt][ct][r] + bb[ct] + bf2f(qkro[(size_t)row * 1536 + col]);
                }
            }
    } else {
        // fused per-head row sums (each 64-col wave quadrant = one head)
        const int c0 = jn0 + wc * 64;
        if (c0 < 1024) {
            const int h = (c0 & 511) >> 6;
            float* dst = (c0 < 512) ? qsv : ksv;
#pragma unroll
            for (int mt = 0; mt < 4; ++mt)
#pragma unroll
                for (int r = 0; r < 4; ++r) {
                    float v = (acc[mt][0][r] + bb[0]) + (acc[mt][1][r] + bb[1]) +
                              (acc[mt][2][r] + bb[2]) + (acc[mt][3][r] + bb[3]);
                    v += __shfl_xor(v, 1); v += __shfl_xor(v, 2);
                    v += __shfl_xor(v, 4); v += __shfl_xor(v, 8);
                    if (s == 0) {
                        const int row = bm + wr * 64 + mt * 16 + quad * 4 + r;
                        dst[((((row >> 10) << 3) + h) << 10) | (row & 1023)] = v;
                    }
                }
        }
        // bf16 pack + coalesced store via LDS bounce (two 64-row halves)
#pragma unroll
        for (int half = 0; half < 2; ++half) {
            __syncthreads();
            if (wr == half) {
#pragma unroll
                for (int mt = 0; mt < 4; ++mt)
#pragma unroll
                    for (int ct = 0; ct < 4; ++ct)
#pragma unroll
                        for (int r = 0; r < 4; ++r)
                            S[(mt * 16 + quad * 4 + r) * 128 + wc * 64 + ct * 16 + s] =
                                f2bf(acc[mt][ct][r] + bb[ct]);
            }
            __syncthreads();
            const int row = t >> 2, coff = (t & 3) * 32;
            u16* dp = Cws + (size_t)(bm + half * 64 + row) * 1536 + jn0 + coff;
#pragma unroll
            for (int i = 0; i < 4; ++i)
                *(uint4*)(dp + i * 8) = *(const uint4*)&S[row * 128 + coff + i * 8];
        }
    }
}

// ---------------------------------------------------------------------------
// Softmax stage (round-7 structure: 64 n-rows x one (b,h), wave w covers
// m in [w*256,(w+1)*256), no unroll/prefetch). ONE change vs round 7:
// __launch_bounds__(256,4) pins VGPR <=128 -> 4 waves/SIMD.
//   stage1<false>: qcol0=0,   rowscale=null, wv=qs
//   stage2<true>:  qcol0=512, rowscale=qg,   wv=qg*ks  (+ U=V*kg tail)
// ---------------------------------------------------------------------------
template <bool DOU>
__global__ __launch_bounds__(256, 4) void stage_soft(
    u16* __restrict__ qkws, int qcol0,
    const u16* __restrict__ wmb, const float* __restrict__ biasv,
    const float* __restrict__ rowscale,
    const float* __restrict__ wv1, const float* __restrict__ wv2,
    float* __restrict__ outg)
{
    __shared__ float zr[4][64], wrs[4][64], kgv[64];
    const int t = threadIdx.x;
    const int w = t >> 6, lane = t & 63, s = lane & 15, quad = lane >> 4;
    const int n0 = blockIdx.x * 64;
    const int bh = blockIdx.y, b = bh >> 3, h = bh & 7;

    short8 qa[4][2];
#pragma unroll
    for (int nt = 0; nt < 4; ++nt)
#pragma unroll
        for (int kk = 0; kk < 2; ++kk)
            qa[nt][kk] = *(const short8*)&qkws[
                (size_t)((b << 10) + n0 + nt * 16 + s) * 1536 + qcol0 + (h << 6) + kk * 32 + quad * 8];

    float rs[4][4];
#pragma unroll
    for (int nt = 0; nt < 4; ++nt)
#pragma unroll
        for (int r = 0; r < 4; ++r)
            rs[nt][r] = rowscale ? rowscale[(bh << 10) + n0 + nt * 16 + quad * 4 + r] : 1.0f;

    float z[4][4] = {}, wa[4][4] = {};

    for (int mi = 0; mi < 16; ++mi) {
        const int mt = w * 256 + mi * 16;
        const u16* bp = wmb + (size_t)(mt + s) * 64 + quad * 8;
        short8 bf0 = *(const short8*)bp;
        short8 bf1 = *(const short8*)(bp + 32);
        const float bm = biasv[mt + s];
        float wv = wv1[(bh << 10) + mt + s];
        if (wv2) wv *= wv2[(bh << 10) + mt + s];
#pragma unroll
        for (int nt = 0; nt < 4; ++nt) {
            f32x4 a = (f32x4){0.f, 0.f, 0.f, 0.f};
            a = MFMA16(qa[nt][0], bf0, a);
            a = MFMA16(qa[nt][1], bf1, a);
#pragma unroll
            for (int r = 0; r < 4; ++r) {
                const float l = (rs[nt][r] * a[r] + bm) * SCL;
                const float e = __expf(l);
                z[nt][r] += e;
                wa[nt][r] += e * wv;
            }
        }
    }

#pragma unroll
    for (int nt = 0; nt < 4; ++nt)
#pragma unroll
        for (int r = 0; r < 4; ++r) {
            float Z = z[nt][r], W = wa[nt][r];
            for (int off = 1; off < 16; off <<= 1) {
                Z += __shfl_xor(Z, off);
                W += __shfl_xor(W, off);
            }
            if (s == 0) {
                zr[w][nt * 16 + quad * 4 + r] = Z;
                wrs[w][nt * 16 + quad * 4 + r] = W;
            }
        }
    __syncthreads();
    if (t < 64) {
        const float Z = zr[0][t] + zr[1][t] + zr[2][t] + zr[3][t];
        const float W = wrs[0][t] + wrs[1][t] + wrs[2][t] + wrs[3][t];
        const float v = W / Z;
        outg[(bh << 10) + n0 + t] = v;
        kgv[t] = v;
    }
    if constexpr (DOU) {
        __syncthreads();
        const int rl = t >> 2, d0 = (t & 3) * 16;
        const float kgf = kgv[rl];
        const size_t base = (size_t)((b << 10) + n0 + rl) * 1536 + (h << 6) + d0;
#pragma unroll
        for (int i = 0; i < 2; ++i) {
            union { uint4 q; u16 u[8]; } vv;
            vv.q = *(const uint4*)&qkws[base + 1024 + i * 8];
            float tmp[8];
#pragma unroll
            for (int j = 0; j < 8; ++j) tmp[j] = bf2f(vv.u[j]) * kgf;
            *(uint4*)&qkws[base + 512 + i * 8] = pack8(tmp);
        }
    }
}

// ---------------------------------------------------------------------------
extern "C" void kernel_launch(void* const* d_in, const int* in_sizes, int n_in,
                              void* d_out, int out_size, void* d_ws, size_t ws_size,
                              hipStream_t stream)
{
    const float* x     = (const float*)d_in[0];
    const float* w_qkv = (const float*)d_in[1];
    const float* b_qkv = (const float*)d_in[2];
    const float* wq    = (const float*)d_in[3];
    const float* bq    = (const float*)d_in[4];
    const float* wk    = (const float*)d_in[5];
    const float* bk    = (const float*)d_in[6];
    const float* w_out = (const float*)d_in[7];
    const float* b_out = (const float*)d_in[8];
    float* out = (float*)d_out;

    // ws: qs|ks|qg|kg (65536 f32) | bf16: wqkv|wout|wq|wk|x | qkv ws bf16
    float* qs = (float*)d_ws;
    float* ks = qs + 65536;
    float* qg = ks + 65536;
    float* kg = qg + 65536;
    u16* wsb   = (u16*)(kg + 65536);
    u16* wqkvb = wsb;
    u16* woutb = wqkvb + 786432;
    u16* wqb   = woutb + 262144;
    u16* wkb   = wqb + 65536;
    u16* xb    = wkb + 65536;
    u16* qkws  = xb + 4194304;

    conv_kernel<<<5248, 256, 0, stream>>>(w_qkv, w_out, wq, wk, x, wsb);
    // QKV GEMM + fused qs/ks rowsums
    gemm128<MQKV><<<dim3(64, 12), 256, 0, stream>>>(
        xb, 512, 0, wqkvb, 512, b_qkv, nullptr, qs, ks, qkws, nullptr);
    // stage 1 -> qg
    stage_soft<false><<<dim3(16, 64), 256, 0, stream>>>(
        qkws, 0, wqb, bq, nullptr, qs, nullptr, qg);
    // stage 2 -> kg, + fused U = V*kg into k-half
    stage_soft<true><<<dim3(16, 64), 256, 0, stream>>>(
        qkws, 512, wkb, bk, qg, qg, ks, kg);
    // OUT: out = U @ w_out^T + b_out + qo
    gemm128<MOUT><<<dim3(64, 4), 256, 0, stream>>>(
        qkws, 1536, 512, woutb, 512, b_out, qkws, nullptr, nullptr, nullptr, out);
}

// Round 12
// 191.714 us; speedup vs baseline: 1.4343x; 1.0008x over previous
//
#include <hip/hip_runtime.h>

// Fastformer additive attention, MI355X (round 11): m97-style GEMMs.
// gemm128 rewritten: BK=64, async global_load_lds (width 16) staging, two
// barriers per k-tile, no VGPR round-trip. Stages/conv identical to the
// 190-us round-7/11 baseline.
//   conv:  w_qkv|w_out|wq|wk|x  f32 -> bf16 (ws)
//   QKV:   qkv[8192][1536] = x @ w_qkv^T + b_qkv (+ fused qs/ks rowsums)
//   stage1: qg = softmax((q.wq+bq)*S) . qs
//   stage2: kg = softmax((qg*(k.wk)+bk)*S) . (qg*ks)  (+ fused U = V*kg)
//   OUT:   out = U @ w_out^T + b_out + qo
// Logits bounded (|l|<~2) -> softmax without max subtraction, z/w linear.

#define SCL 0.125f
typedef unsigned short u16;
typedef __attribute__((ext_vector_type(8))) short short8;   // 8 bf16 = 4 VGPR
typedef __attribute__((ext_vector_type(4))) float f32x4;

#define MFMA16(a, b, c) __builtin_amdgcn_mfma_f32_16x16x32_bf16((a), (b), (c), 0, 0, 0)

__device__ __forceinline__ float bf2f(u16 u) {
    union { unsigned int i; float f; } v; v.i = ((unsigned int)u) << 16; return v.f;
}
__device__ __forceinline__ u16 f2bf(float f) {
    union { float f; unsigned int i; } v; v.f = f;
    unsigned int x = v.i;
    return (u16)((x + 0x7FFFu + ((x >> 16) & 1u)) >> 16);
}
__device__ __forceinline__ uint4 pack8(const float* v) {
    union { u16 u[8]; uint4 q; } r;
#pragma unroll
    for (int i = 0; i < 8; ++i) r.u[i] = f2bf(v[i]);
    return r.q;
}
// async 16B/lane global -> LDS (wave-uniform LDS base + lane*16)
__device__ __forceinline__ void async16(const u16* g, u16* l) {
    __builtin_amdgcn_global_load_lds(
        (const __attribute__((address_space(1))) void*)g,
        (__attribute__((address_space(3))) void*)l, 16, 0, 0);
}

// ---------------------------------------------------------------------------
// f32 -> bf16: w_qkv | w_out | wq | wk | x   (contiguous ws block)
// ---------------------------------------------------------------------------
__global__ __launch_bounds__(256) void conv_kernel(
    const float* __restrict__ w_qkv, const float* __restrict__ w_out,
    const float* __restrict__ wq, const float* __restrict__ wk,
    const float* __restrict__ x, u16* __restrict__ wsb)
{
    const int idx = (blockIdx.x * 256 + threadIdx.x) * 4;
    const float* src; int off;
    if      (idx < 786432)  { src = w_qkv; off = idx; }
    else if (idx < 1048576) { src = w_out; off = idx - 786432; }
    else if (idx < 1114112) { src = wq;    off = idx - 1048576; }
    else if (idx < 1179648) { src = wk;    off = idx - 1114112; }
    else                    { src = x;     off = idx - 1179648; }
    float4 v = *(const float4*)(src + off);
    ushort4 o; o.x = f2bf(v.x); o.y = f2bf(v.y); o.z = f2bf(v.z); o.w = f2bf(v.w);
    *(ushort4*)(wsb + idx) = o;
}

// ---------------------------------------------------------------------------
// 128x128 MFMA GEMM, BK=64, K=512, 256 thr (4 waves, 2x2 quadrants of 64x64).
// Staging via async global_load_lds dwordx4: per k-tile each wave issues
// 4 A-chunks + 4 B-chunks (8 rows x 64k each, lane i -> row i>>3, koff
// (i&7)*8; LDS row-major stride 64 u16 -> lane*16 contiguous). Barrier
// drains vmcnt (m97 pattern).
//  MQKV: C=bf16 qkv ws (+b_qkv), fused per-head rowsums -> qs/ks
//  MOUT: C=f32 out (+b_out + qo residual from q-half of qkv ws)
// ---------------------------------------------------------------------------
#define MQKV 0
#define MOUT 1

template <int MODE>
__global__ __launch_bounds__(256) void gemm128(
    const u16* __restrict__ Ab, int lda, int acol,
    const u16* __restrict__ Wb, int ldb,
    const float* __restrict__ biasf,
    const u16* __restrict__ qkro,
    float* __restrict__ qsv, float* __restrict__ ksv,
    u16* __restrict__ Cws, float* __restrict__ outp)
{
    __shared__ u16 As[128 * 64];     // 16 KB
    __shared__ u16 Bs[128 * 64];     // 16 KB

    const int t = threadIdx.x;
    const int w = t >> 6, lane = t & 63, s = lane & 15, quad = lane >> 4;
    const int wr = w >> 1, wc = w & 1;
    const int bm = blockIdx.x * 128, jn0 = blockIdx.y * 128;
    const int wu = __builtin_amdgcn_readfirstlane(w);
    const int lrow = lane >> 3;          // row within 8-row chunk
    const int lkc  = (lane & 7) * 8;     // k offset within 64

    f32x4 acc[4][4];
#pragma unroll
    for (int i = 0; i < 4; ++i)
#pragma unroll
        for (int j = 0; j < 4; ++j) acc[i][j] = (f32x4){0.f, 0.f, 0.f, 0.f};

    for (int kt = 0; kt < 512; kt += 64) {
        __syncthreads();   // all waves done reading previous tile
#pragma unroll
        for (int c = 0; c < 4; ++c) {
            const int row = wu * 32 + c * 8;
            async16(Ab + (size_t)(bm + row + lrow) * lda + acol + kt + lkc,
                    As + row * 64);
            async16(Wb + (size_t)(jn0 + row + lrow) * ldb + kt + lkc,
                    Bs + row * 64);
        }
        __syncthreads();   // drains vmcnt -> tile visible
#pragma unroll
        for (int kk = 0; kk < 2; ++kk) {
            short8 af[4], bf[4];
#pragma unroll
            for (int mt = 0; mt < 4; ++mt)
                af[mt] = *(const short8*)&As[(wr * 64 + mt * 16 + s) * 64 + kk * 32 + quad * 8];
#pragma unroll
            for (int ct = 0; ct < 4; ++ct)
                bf[ct] = *(const short8*)&Bs[(wc * 64 + ct * 16 + s) * 64 + kk * 32 + quad * 8];
#pragma unroll
            for (int mt = 0; mt < 4; ++mt)
#pragma unroll
                for (int ct = 0; ct < 4; ++ct)
                    acc[mt][ct] = MFMA16(af[mt], bf[ct], acc[mt][ct]);
        }
    }

    float bb[4];
#pragma unroll
    for (int ct = 0; ct < 4; ++ct) bb[ct] = biasf[jn0 + wc * 64 + ct * 16 + s];

    if constexpr (MODE == MOUT) {
#pragma unroll
        for (int mt = 0; mt < 4; ++mt)
#pragma unroll
            for (int ct = 0; ct < 4; ++ct) {
                const int col = jn0 + wc * 64 + ct * 16 + s;
#pragma unroll
                for (int r = 0; r < 4; ++r) {
                    const int row = bm + wr * 64 + mt * 16 + quad * 4 + r;
                    outp[(size_t)row * 512 + col] =
                        acc[mt][ct][r] + bb[ct] + bf2f(qkro[(size_t)row * 1536 + col]);
                }
            }
    } else {
        // fused per-head row sums (each 64-col wave quadrant = one head)
        const int c0 = jn0 + wc * 64;
        if (c0 < 1024) {
            const int h = (c0 & 511) >> 6;
            float* dst = (c0 < 512) ? qsv : ksv;
#pragma unroll
            for (int mt = 0; mt < 4; ++mt)
#pragma unroll
                for (int r = 0; r < 4; ++r) {
                    float v = (acc[mt][0][r] + bb[0]) + (acc[mt][1][r] + bb[1]) +
                              (acc[mt][2][r] + bb[2]) + (acc[mt][3][r] + bb[3]);
                    v += __shfl_xor(v, 1); v += __shfl_xor(v, 2);
                    v += __shfl_xor(v, 4); v += __shfl_xor(v, 8);
                    if (s == 0) {
                        const int row = bm + wr * 64 + mt * 16 + quad * 4 + r;
                        dst[((((row >> 10) << 3) + h) << 10) | (row & 1023)] = v;
                    }
                }
        }
        // bf16 pack + coalesced store via LDS bounce (two 64-row halves)
#pragma unroll
        for (int half = 0; half < 2; ++half) {
            __syncthreads();
            if (wr == half) {
#pragma unroll
                for (int mt = 0; mt < 4; ++mt)
#pragma unroll
                    for (int ct = 0; ct < 4; ++ct)
#pragma unroll
                        for (int r = 0; r < 4; ++r)
                            As[(mt * 16 + quad * 4 + r) * 128 + wc * 64 + ct * 16 + s] =
                                f2bf(acc[mt][ct][r] + bb[ct]);
            }
            __syncthreads();
            const int row = t >> 2, coff = (t & 3) * 32;
            u16* dp = Cws + (size_t)(bm + half * 64 + row) * 1536 + jn0 + coff;
#pragma unroll
            for (int i = 0; i < 4; ++i)
                *(uint4*)(dp + i * 8) = *(const uint4*)&As[row * 128 + coff + i * 8];
        }
    }
}

// ---------------------------------------------------------------------------
// Softmax stage (round-7 structure, unchanged: 64 n-rows x one (b,h), wave w
// covers m in [w*256,(w+1)*256), launch_bounds(256,4)).
//   stage1<false>: qcol0=0,   rowscale=null, wv=qs
//   stage2<true>:  qcol0=512, rowscale=qg,   wv=qg*ks  (+ U=V*kg tail)
// ---------------------------------------------------------------------------
template <bool DOU>
__global__ __launch_bounds__(256, 4) void stage_soft(
    u16* __restrict__ qkws, int qcol0,
    const u16* __restrict__ wmb, const float* __restrict__ biasv,
    const float* __restrict__ rowscale,
    const float* __restrict__ wv1, const float* __restrict__ wv2,
    float* __restrict__ outg)
{
    __shared__ float zr[4][64], wrs[4][64], kgv[64];
    const int t = threadIdx.x;
    const int w = t >> 6, lane = t & 63, s = lane & 15, quad = lane >> 4;
    const int n0 = blockIdx.x * 64;
    const int bh = blockIdx.y, b = bh >> 3, h = bh & 7;

    short8 qa[4][2];
#pragma unroll
    for (int nt = 0; nt < 4; ++nt)
#pragma unroll
        for (int kk = 0; kk < 2; ++kk)
            qa[nt][kk] = *(const short8*)&qkws[
                (size_t)((b << 10) + n0 + nt * 16 + s) * 1536 + qcol0 + (h << 6) + kk * 32 + quad * 8];

    float rs[4][4];
#pragma unroll
    for (int nt = 0; nt < 4; ++nt)
#pragma unroll
        for (int r = 0; r < 4; ++r)
            rs[nt][r] = rowscale ? rowscale[(bh << 10) + n0 + nt * 16 + quad * 4 + r] : 1.0f;

    float z[4][4] = {}, wa[4][4] = {};

    for (int mi = 0; mi < 16; ++mi) {
        const int mt = w * 256 + mi * 16;
        const u16* bp = wmb + (size_t)(mt + s) * 64 + quad * 8;
        short8 bf0 = *(const short8*)bp;
        short8 bf1 = *(const short8*)(bp + 32);
        const float bm = biasv[mt + s];
        float wv = wv1[(bh << 10) + mt + s];
        if (wv2) wv *= wv2[(bh << 10) + mt + s];
#pragma unroll
        for (int nt = 0; nt < 4; ++nt) {
            f32x4 a = (f32x4){0.f, 0.f, 0.f, 0.f};
            a = MFMA16(qa[nt][0], bf0, a);
            a = MFMA16(qa[nt][1], bf1, a);
#pragma unroll
            for (int r = 0; r < 4; ++r) {
                const float l = (rs[nt][r] * a[r] + bm) * SCL;
                const float e = __expf(l);
                z[nt][r] += e;
                wa[nt][r] += e * wv;
            }
        }
    }

#pragma unroll
    for (int nt = 0; nt < 4; ++nt)
#pragma unroll
        for (int r = 0; r < 4; ++r) {
            float Z = z[nt][r], W = wa[nt][r];
            for (int off = 1; off < 16; off <<= 1) {
                Z += __shfl_xor(Z, off);
                W += __shfl_xor(W, off);
            }
            if (s == 0) {
                zr[w][nt * 16 + quad * 4 + r] = Z;
                wrs[w][nt * 16 + quad * 4 + r] = W;
            }
        }
    __syncthreads();
    if (t < 64) {
        const float Z = zr[0][t] + zr[1][t] + zr[2][t] + zr[3][t];
        const float W = wrs[0][t] + wrs[1][t] + wrs[2][t] + wrs[3][t];
        const float v = W / Z;
        outg[(bh << 10) + n0 + t] = v;
        kgv[t] = v;
    }
    if constexpr (DOU) {
        __syncthreads();
        const int rl = t >> 2, d0 = (t & 3) * 16;
        const float kgf = kgv[rl];
        const size_t base = (size_t)((b << 10) + n0 + rl) * 1536 + (h << 6) + d0;
#pragma unroll
        for (int i = 0; i < 2; ++i) {
            union { uint4 q; u16 u[8]; } vv;
            vv.q = *(const uint4*)&qkws[base + 1024 + i * 8];
            float tmp[8];
#pragma unroll
            for (int j = 0; j < 8; ++j) tmp[j] = bf2f(vv.u[j]) * kgf;
            *(uint4*)&qkws[base + 512 + i * 8] = pack8(tmp);
        }
    }
}

// ---------------------------------------------------------------------------
extern "C" void kernel_launch(void* const* d_in, const int* in_sizes, int n_in,
                              void* d_out, int out_size, void* d_ws, size_t ws_size,
                              hipStream_t stream)
{
    const float* x     = (const float*)d_in[0];
    const float* w_qkv = (const float*)d_in[1];
    const float* b_qkv = (const float*)d_in[2];
    const float* wq    = (const float*)d_in[3];
    const float* bq    = (const float*)d_in[4];
    const float* wk    = (const float*)d_in[5];
    const float* bk    = (const float*)d_in[6];
    const float* w_out = (const float*)d_in[7];
    const float* b_out = (const float*)d_in[8];
    float* out = (float*)d_out;

    // ws: qs|ks|qg|kg (65536 f32) | bf16: wqkv|wout|wq|wk|x | qkv ws bf16
    float* qs = (float*)d_ws;
    float* ks = qs + 65536;
    float* qg = ks + 65536;
    float* kg = qg + 65536;
    u16* wsb   = (u16*)(kg + 65536);
    u16* wqkvb = wsb;
    u16* woutb = wqkvb + 786432;
    u16* wqb   = woutb + 262144;
    u16* wkb   = wqb + 65536;
    u16* xb    = wkb + 65536;
    u16* qkws  = xb + 4194304;

    conv_kernel<<<5248, 256, 0, stream>>>(w_qkv, w_out, wq, wk, x, wsb);
    // QKV GEMM + fused qs/ks rowsums
    gemm128<MQKV><<<dim3(64, 12), 256, 0, stream>>>(
        xb, 512, 0, wqkvb, 512, b_qkv, nullptr, qs, ks, qkws, nullptr);
    // stage 1 -> qg
    stage_soft<false><<<dim3(16, 64), 256, 0, stream>>>(
        qkws, 0, wqb, bq, nullptr, qs, nullptr, qg);
    // stage 2 -> kg, + fused U = V*kg into k-half
    stage_soft<true><<<dim3(16, 64), 256, 0, stream>>>(
        qkws, 512, wkb, bk, qg, qg, ks, kg);
    // OUT: out = U @ w_out^T + b_out + qo
    gemm128<MOUT><<<dim3(64, 4), 256, 0, stream>>>(
        qkws, 1536, 512, woutb, 512, b_out, qkws, nullptr, nullptr, nullptr, out);
}